// Round 15
// baseline (211.331 us; speedup 1.0000x reference)
//
#include <hip/hip_runtime.h>
#include <hip/hip_bf16.h>

#define N_NODES 10000
#define KNEI    30
#define DIM     128
#define EDGES   (N_NODES * KNEI)

typedef __attribute__((ext_vector_type(4))) float  f32x4;
typedef __attribute__((ext_vector_type(8))) __bf16 bf16x8;
typedef __attribute__((ext_vector_type(4))) __bf16 bf16x4;

// packed bf16 weight offsets in d_ws (element units); per-matrix fragment tiles
// AW1 (K=384, kt0..3 = hi part, kt4..11 = e|hj), others K=128/256, Ntiles=8.
// A3 = att_w3 [128][4] zero-padded to N=16. THT/HIT = row-major transposed
// copies thw^T[d][k], W1hi^T[f][k] for the in-kernel matvec epilogues.
#define OFF_AW1 0        // 96 tiles
#define OFF_AW2 49152    // 32 tiles
#define OFF_NW1 65536    // 64 tiles
#define OFF_NW2 98304    // 32 tiles
#define OFF_NW3 114688   // 32 tiles
#define OFF_TH  131072   // 32 tiles (unused now, kept for layout stability)
#define OFF_A3  147456   // 4 tiles
#define OFF_THT 149504   // 16384 elems: thw^T
#define OFF_HIT 165888   // 16384 elems: W1hi^T (= att_w1 rows 0..127 ^T)
#define TOT_ELEMS 182272 // 292*512 + 2*16384

// Pack all weights (f32) into MFMA A-fragment order (+ two plain transposes),
// bf16, one launch. tile = kt*8+nt; lane holds n = nt*16+(lane&15).
__global__ __launch_bounds__(256) void repack_all(
    const float* __restrict__ aw1, const float* __restrict__ aw2,
    const float* __restrict__ nw1, const float* __restrict__ nw2,
    const float* __restrict__ nw3, const float* __restrict__ thw,
    const float* __restrict__ aw3, __bf16* __restrict__ dst) {
    int t = blockIdx.x * 256 + threadIdx.x;
    if (t >= TOT_ELEMS) return;
    float v;
    if (t >= 292 * 512) {                // THT / HIT plain transposes
        int t2 = t - 292 * 512;
        int arr = t2 >> 14;              // 0: thw^T, 1: W1hi^T
        int e2  = t2 & 16383;
        int row = e2 >> 7;               // d (or f)
        int k   = e2 & 127;
        v = arr == 0 ? thw[k * 128 + row] : aw1[k * 128 + row];
    } else {
        int tile = t >> 9;
        int i    = t & 7;
        int lane = (t >> 3) & 63;
        int krow = ((lane >> 4) << 3) + i;
        int ncol = lane & 15;
        if (tile >= 288) {               // A3: aw3 [128][4] padded to 16 cols
            int k = (tile - 288) * 32 + krow;
            v = (ncol < 4) ? aw3[k * 4 + ncol] : 0.f;
        } else {
            const float* src; int lt;
            if      (tile < 96)  { src = aw1; lt = tile; }        // K=384
            else if (tile < 128) { src = aw2; lt = tile - 96; }
            else if (tile < 192) { src = nw1; lt = tile - 128; }  // K=256
            else if (tile < 224) { src = nw2; lt = tile - 192; }
            else if (tile < 256) { src = nw3; lt = tile - 224; }
            else                 { src = thw; lt = tile - 256; }
            int nt = lt & 7;
            int kt = lt >> 3;
            v = src[(kt * 32 + krow) * DIM + nt * 16 + ncol];
        }
    }
    dst[t] = (__bf16)v;
}

// fast gelu: 0.5x(1+tanh(u)) = x - x/(exp(2u)+1)  (~8 VALU incl native rcp)
__device__ __forceinline__ float gelu_f(float x) {
    float y = x * fmaf(0.0713548163f, x * x, 1.5957691216f);  // 2u
    float r = __builtin_amdgcn_rcpf(__expf(y) + 1.f);
    return x - x * r;
}

__device__ __forceinline__ bf16x4 cvt4(float4 v) {
    bf16x4 r;
    r[0] = (__bf16)v.x; r[1] = (__bf16)v.y; r[2] = (__bf16)v.z; r[3] = (__bf16)v.w;
    return r;
}

// actmode: 0 = relu, 1 = gelu.
__device__ __forceinline__ void store_act(f32x4 acc[2], const float* __restrict__ bias,
                                          __bf16* y, int sy, int actmode,
                                          int wv, int lane) {
    const int mrow = lane & 15;
    const int kgrp = (lane >> 4) & 3;
    const int nb = wv * 16 + kgrp * 4;
    float b0 = bias[nb], b1 = bias[nb + 1], b2 = bias[nb + 2], b3 = bias[nb + 3];
#pragma unroll
    for (int mf = 0; mf < 2; ++mf) {
        bf16x4 pk;
        float vv[4] = {acc[mf][0] + b0, acc[mf][1] + b1, acc[mf][2] + b2, acc[mf][3] + b3};
#pragma unroll
        for (int r = 0; r < 4; ++r) {
            float v = vv[r];
            v = actmode == 0 ? fmaxf(v, 0.f) : gelu_f(v);
            pk[r] = (__bf16)v;
        }
        *reinterpret_cast<bf16x4*>(y + (mf * 16 + mrow) * sy + nb) = pk;
    }
}

#define ZERO2(A) do { A[0] = (f32x4){0.f,0.f,0.f,0.f}; A[1] = (f32x4){0.f,0.f,0.f,0.f}; } while (0)

// ---- fully-fused kernel: one block = 1 node, 512 thr = 8 waves, 6 barriers ----
// r13 structure (proven 149.4 us) + yhi matvec folded into P0 (sY partials) +
// final projection folded into P5/P6 epilogue (sPre/sAcc) -> 2 launches total.
// Occupancy law (r1..r14): waves/SIMD ~ floor(256/VGPR); keep VGPR minimal.
// r14 lesson: trading occupancy (84->44%) for fewer LDS reads is a net loss.
__global__ __launch_bounds__(512, 4) void gnn_fused(
    const float* __restrict__ h, const float* __restrict__ e, const int* __restrict__ eidx,
    const float* __restrict__ ab1, const float* __restrict__ ab2, const float* __restrict__ ab3,
    const float* __restrict__ nb1, const float* __restrict__ nb2, const float* __restrict__ nb3,
    const __bf16* __restrict__ wp, float* __restrict__ out) {

    __shared__ __bf16 S[8704];        // staging e|hj (stride 264, 8448 used);
                                      // after P1: S' = node2-out @0, A2 = att2-out @4352 (stride 136)
    __shared__ __bf16 Y1[32 * 136];   // att1-out
    __shared__ __bf16 Y2[32 * 136];   // node1-out
    __shared__ float  sW[32][4];      // softmax weights (rows 30/31 = 0)
    __shared__ float  sY[4][128];     // yhi k-quarter partials (h[node] @ W1hi^T)
    __shared__ float  sPre[128];      // aggregated pre-projection row
    __shared__ float  sAcc[4][128];   // projection k-quarter partials

    const int tid  = threadIdx.x;
    const int wv   = tid >> 6;
    const int lane = tid & 63;
    const int mrow = lane & 15;
    const int kg   = (lane >> 4) & 3;
    const int node = blockIdx.x;
    const long ebase = (long)node * KNEI;

    // ---- P0: stage e|hj (f32 -> bf16), pad rows 30/31 = 0 ----
#pragma unroll
    for (int c = 0; c < 2; ++c) {
        int idx = c * 512 + tid;
        int m  = idx >> 5;   // row 0..31
        int jv = idx & 31;   // float4 col
        float4 ev = make_float4(0.f, 0.f, 0.f, 0.f), hjv = ev;
        if (m < KNEI) {
            long ge = ebase + m;
            ev  = *reinterpret_cast<const float4*>(e + ge * DIM + jv * 4);
            int dstn = eidx[EDGES + ge];
            hjv = *reinterpret_cast<const float4*>(h + (long)dstn * DIM + jv * 4);
        }
        *reinterpret_cast<bf16x4*>(&S[m * 264 + jv * 4])       = cvt4(ev);
        *reinterpret_cast<bf16x4*>(&S[m * 264 + 128 + jv * 4]) = cvt4(hjv);
    }
    // yhi partials: sY[kq][f] = sum_j h[node][kq*32+j] * W1hi[kq*32+j][f]
    {
        const int kq = tid >> 7, f = tid & 127;
        const float*  hrow = h + (long)node * DIM + kq * 32;
        const __bf16* wrow = wp + OFF_HIT + f * 128 + kq * 32;
        float a = 0.f;
#pragma unroll
        for (int j = 0; j < 32; j += 8) {
            bf16x8 w8 = *reinterpret_cast<const bf16x8*>(wrow + j);
            float4 h0 = *reinterpret_cast<const float4*>(hrow + j);
            float4 h1 = *reinterpret_cast<const float4*>(hrow + j + 4);
            a += (float)w8[0] * h0.x + (float)w8[1] * h0.y + (float)w8[2] * h0.z + (float)w8[3] * h0.w
               + (float)w8[4] * h1.x + (float)w8[5] * h1.y + (float)w8[6] * h1.z + (float)w8[7] * h1.w;
        }
        sY[kq][f] = a;
    }
    __syncthreads();   // b0

    // ---- P1: MERGED layer-1 (K=256): att1 & node1 share S b-reads ----
    {
        f32x4 aa[2], an[2];
        ZERO2(aa); ZERO2(an);
        const __bf16* wA = wp + OFF_AW1 + 16384;   // att_w1 e|hj part (kt 4..11)
        const __bf16* wN = wp + OFF_NW1;
#pragma unroll
        for (int kt = 0; kt < 8; ++kt) {
            const int kb = kt * 32 + kg * 8;
            bf16x8 b0 = *reinterpret_cast<const bf16x8*>(S + mrow * 264 + kb);
            bf16x8 b1 = *reinterpret_cast<const bf16x8*>(S + (16 + mrow) * 264 + kb);
            bf16x8 a0 = *reinterpret_cast<const bf16x8*>(wA + ((kt * 8 + wv) * 64 + lane) * 8);
            aa[0] = __builtin_amdgcn_mfma_f32_16x16x32_bf16(a0, b0, aa[0], 0, 0, 0);
            aa[1] = __builtin_amdgcn_mfma_f32_16x16x32_bf16(a0, b1, aa[1], 0, 0, 0);
            bf16x8 a1 = *reinterpret_cast<const bf16x8*>(wN + ((kt * 8 + wv) * 64 + lane) * 8);
            an[0] = __builtin_amdgcn_mfma_f32_16x16x32_bf16(a1, b0, an[0], 0, 0, 0);
            an[1] = __builtin_amdgcn_mfma_f32_16x16x32_bf16(a1, b1, an[1], 0, 0, 0);
        }
        // att epilogue: bias = ab1 + sum_q sY[q]  (yhi computed in-block)
        {
            const int nb = wv * 16 + kg * 4;
            float4 a1v = *reinterpret_cast<const float4*>(ab1 + nb);
            float bav[4] = {a1v.x, a1v.y, a1v.z, a1v.w};
#pragma unroll
            for (int q = 0; q < 4; ++q) {
                float4 sq = *reinterpret_cast<float4*>(&sY[q][nb]);
                bav[0] += sq.x; bav[1] += sq.y; bav[2] += sq.z; bav[3] += sq.w;
            }
#pragma unroll
            for (int mf = 0; mf < 2; ++mf) {
                bf16x4 pk;
#pragma unroll
                for (int r = 0; r < 4; ++r)
                    pk[r] = (__bf16)fmaxf(aa[mf][r] + bav[r], 0.f);
                *reinterpret_cast<bf16x4*>(Y1 + (mf * 16 + mrow) * 136 + nb) = pk;
            }
        }
        store_act(an, nb1, Y2, 136, 1, wv, lane);
    }
    __syncthreads();   // b1 (S reads done; S free for S'/A2)

    // ---- P2: wave-split layer-2 (K=128): att2 -> A2 (relu), node2 -> S' (gelu) ----
    {
        const bool isatt = (wv < 4);
        const int w4 = isatt ? wv : (wv - 4);
        const __bf16* B = isatt ? Y1 : Y2;
        const __bf16* W = wp + (isatt ? OFF_AW2 : OFF_NW2);
        const float* bias = isatt ? ab2 : nb2;
        __bf16* dst = S + (isatt ? 4352 : 0);
        f32x4 acc[2][2];
        ZERO2(acc[0]); ZERO2(acc[1]);
#pragma unroll
        for (int kt = 0; kt < 4; ++kt) {
            const int kb = kt * 32 + kg * 8;
            bf16x8 b0 = *reinterpret_cast<const bf16x8*>(B + mrow * 136 + kb);
            bf16x8 b1 = *reinterpret_cast<const bf16x8*>(B + (16 + mrow) * 136 + kb);
#pragma unroll
            for (int j = 0; j < 2; ++j) {
                bf16x8 a = *reinterpret_cast<const bf16x8*>(W + (size_t)((kt * 8 + w4 * 2 + j) * 64 + lane) * 8);
                acc[j][0] = __builtin_amdgcn_mfma_f32_16x16x32_bf16(a, b0, acc[j][0], 0, 0, 0);
                acc[j][1] = __builtin_amdgcn_mfma_f32_16x16x32_bf16(a, b1, acc[j][1], 0, 0, 0);
            }
        }
#pragma unroll
        for (int j = 0; j < 2; ++j) {
            const int f = w4 * 32 + j * 16 + kg * 4;
            float b0 = bias[f], b1 = bias[f + 1], b2 = bias[f + 2], b3 = bias[f + 3];
#pragma unroll
            for (int mf = 0; mf < 2; ++mf) {
                float vv[4] = {acc[j][mf][0] + b0, acc[j][mf][1] + b1,
                               acc[j][mf][2] + b2, acc[j][mf][3] + b3};
                bf16x4 pk;
#pragma unroll
                for (int r = 0; r < 4; ++r) {
                    float v = vv[r];
                    pk[r] = (__bf16)(isatt ? fmaxf(v, 0.f) : gelu_f(v));
                }
                *reinterpret_cast<bf16x4*>(dst + (mf * 16 + mrow) * 136 + f) = pk;
            }
        }
    }
    __syncthreads();   // b2 (Y1/Y2 reads done; S' and A2 ready)

    // ---- P3: wave 0: logits via MFMA + softmax; all waves: node3 (V in regs) ----
    if (wv == 0) {
        const __bf16* A2 = S + 4352;
        f32x4 la[2];
        ZERO2(la);
#pragma unroll
        for (int kt = 0; kt < 4; ++kt) {
            const int kb = kt * 32 + kg * 8;
            bf16x8 b0 = *reinterpret_cast<const bf16x8*>(A2 + mrow * 136 + kb);
            bf16x8 b1 = *reinterpret_cast<const bf16x8*>(A2 + (16 + mrow) * 136 + kb);
            bf16x8 a = *reinterpret_cast<const bf16x8*>(wp + OFF_A3 + ((kt * 64) + lane) * 8);
            la[0] = __builtin_amdgcn_mfma_f32_16x16x32_bf16(a, b0, la[0], 0, 0, 0);
            la[1] = __builtin_amdgcn_mfma_f32_16x16x32_bf16(a, b1, la[1], 0, 0, 0);
        }
        if (lane < 16) {   // lane = edge m; heads 0-3 in regs (kg==0 slice)
            const float sc = 0.17677669529f;   // 1/sqrt(32)
            float v0[4], v1[4], mx[4];
            const bool pad1 = (16 + lane) >= KNEI;
#pragma unroll
            for (int r = 0; r < 4; ++r) {
                v0[r] = (la[0][r] + ab3[r]) * sc;
                v1[r] = pad1 ? -1e30f : (la[1][r] + ab3[r]) * sc;
                mx[r] = fmaxf(v0[r], v1[r]);
            }
#pragma unroll
            for (int msk = 1; msk <= 8; msk <<= 1)
#pragma unroll
                for (int r = 0; r < 4; ++r) mx[r] = fmaxf(mx[r], __shfl_xor(mx[r], msk));
            float e0[4], e1[4], sm[4];
#pragma unroll
            for (int r = 0; r < 4; ++r) {
                e0[r] = __expf(v0[r] - mx[r]);
                e1[r] = __expf(v1[r] - mx[r]);   // pad -> 0
                sm[r] = e0[r] + e1[r];
            }
#pragma unroll
            for (int msk = 1; msk <= 8; msk <<= 1)
#pragma unroll
                for (int r = 0; r < 4; ++r) sm[r] += __shfl_xor(sm[r], msk);
            float i0 = __builtin_amdgcn_rcpf(sm[0]), i1 = __builtin_amdgcn_rcpf(sm[1]);
            float i2 = __builtin_amdgcn_rcpf(sm[2]), i3 = __builtin_amdgcn_rcpf(sm[3]);
            float4 w0 = make_float4(e0[0] * i0, e0[1] * i1, e0[2] * i2, e0[3] * i3);
            float4 w1 = make_float4(e1[0] * i0, e1[1] * i1, e1[2] * i2, e1[3] * i3);
            *reinterpret_cast<float4*>(&sW[lane][0])      = w0;
            *reinterpret_cast<float4*>(&sW[16 + lane][0]) = w1;   // rows 30/31 -> 0
        }
    }
    f32x4 v2[2];
    ZERO2(v2);
#pragma unroll
    for (int kt = 0; kt < 4; ++kt) {
        const int kb = kt * 32 + kg * 8;
        bf16x8 b0 = *reinterpret_cast<const bf16x8*>(S + mrow * 136 + kb);
        bf16x8 b1 = *reinterpret_cast<const bf16x8*>(S + (16 + mrow) * 136 + kb);
        bf16x8 a = *reinterpret_cast<const bf16x8*>(wp + OFF_NW3 + (size_t)((kt * 8 + wv) * 64 + lane) * 8);
        v2[0] = __builtin_amdgcn_mfma_f32_16x16x32_bf16(a, b0, v2[0], 0, 0, 0);
        v2[1] = __builtin_amdgcn_mfma_f32_16x16x32_bf16(a, b1, v2[1], 0, 0, 0);
    }
    __syncthreads();   // b3 (sW visible; V in regs)

    // ---- P4: fused aggregation: sPre[n] = sum_m w[m]*(V+nb3) ----
    {
        const int hh = wv >> 1;           // head of this wave's 16-feature slice
        float wgt0 = sW[mrow][hh];        // edge m = mrow      (mf=0)
        float wgt1 = sW[16 + mrow][hh];   // edge m = 16 + mrow (mf=1)
        float part[4];
#pragma unroll
        for (int r = 0; r < 4; ++r)
            part[r] = wgt0 * v2[0][r] + wgt1 * v2[1][r];
#pragma unroll
        for (int msk = 1; msk <= 8; msk <<= 1)
#pragma unroll
            for (int r = 0; r < 4; ++r)
                part[r] += __shfl_xor(part[r], msk);
        if (mrow == 0) {                  // lanes 0,16,32,48 -> kg 0..3
            const int nb = wv * 16 + kg * 4;
            float4 o = make_float4(part[0] + nb3[nb],     part[1] + nb3[nb + 1],
                                   part[2] + nb3[nb + 2], part[3] + nb3[nb + 3]);
            *reinterpret_cast<float4*>(&sPre[nb]) = o;
        }
    }
    __syncthreads();   // b4 (sPre ready)

    // ---- P5: projection partials: sAcc[kq][d] = sum_j sPre[kq*32+j]*thw[kq*32+j][d] ----
    {
        const int kq = tid >> 7, d = tid & 127;
        const __bf16* wrow = wp + OFF_THT + d * 128 + kq * 32;
        const float*  p    = &sPre[kq * 32];
        float a = 0.f;
#pragma unroll
        for (int j = 0; j < 32; j += 8) {
            bf16x8 w8 = *reinterpret_cast<const bf16x8*>(wrow + j);
            a += (float)w8[0] * p[j]     + (float)w8[1] * p[j + 1]
               + (float)w8[2] * p[j + 2] + (float)w8[3] * p[j + 3]
               + (float)w8[4] * p[j + 4] + (float)w8[5] * p[j + 5]
               + (float)w8[6] * p[j + 6] + (float)w8[7] * p[j + 7];
        }
        sAcc[kq][d] = a;
    }
    __syncthreads();   // b5

    // ---- P6: final combine + store out[node] ----
    if (tid < 128)
        out[(long)node * DIM + tid] = sAcc[0][tid] + sAcc[1][tid] + sAcc[2][tid] + sAcc[3][tid];
}

extern "C" void kernel_launch(void* const* d_in, const int* in_sizes, int n_in,
                              void* d_out, int out_size, void* d_ws, size_t ws_size,
                              hipStream_t stream) {
    const float* h   = (const float*)d_in[0];
    const float* e   = (const float*)d_in[1];
    const int*   ei  = (const int*)d_in[2];
    const float* aw1 = (const float*)d_in[3];
    const float* ab1 = (const float*)d_in[4];
    const float* aw2 = (const float*)d_in[5];
    const float* ab2 = (const float*)d_in[6];
    const float* aw3 = (const float*)d_in[7];
    const float* ab3 = (const float*)d_in[8];
    const float* nw1 = (const float*)d_in[9];
    const float* nb1 = (const float*)d_in[10];
    const float* nw2 = (const float*)d_in[11];
    const float* nb2 = (const float*)d_in[12];
    const float* nw3 = (const float*)d_in[13];
    const float* nb3 = (const float*)d_in[14];
    const float* thw = (const float*)d_in[15];
    float* out = (float*)d_out;
    __bf16* wp = (__bf16*)d_ws;

    // all-weight repack (f32 -> bf16 fragments + 2 transposes), one launch
    repack_all<<<(TOT_ELEMS + 255) / 256, 256, 0, stream>>>(
        aw1, aw2, nw1, nw2, nw3, thw, aw3, wp);

    gnn_fused<<<N_NODES, 512, 0, stream>>>(h, e, ei, ab1, ab2, ab3,
                                           nb1, nb2, nb3, wp, out);
}

// Round 16
// 188.261 us; speedup vs baseline: 1.1225x; 1.1225x over previous
//
#include <hip/hip_runtime.h>
#include <hip/hip_bf16.h>

#define N_NODES 10000
#define KNEI    30
#define DIM     128
#define EDGES   (N_NODES * KNEI)

typedef __attribute__((ext_vector_type(4))) float  f32x4;
typedef __attribute__((ext_vector_type(8))) __bf16 bf16x8;
typedef __attribute__((ext_vector_type(4))) __bf16 bf16x4;

// packed bf16 weight offsets in d_ws (element units); per-matrix fragment tiles
// AW1 (K=384, kt0..3 = hi part, kt4..11 = e|hj), others K=128/256, Ntiles=8.
// A3 = att_w3 [128][4] zero-padded to N=16 (1 n-tile, 4 k-tiles).
#define OFF_AW1 0        // 96 tiles
#define OFF_AW2 49152    // 32 tiles
#define OFF_NW1 65536    // 64 tiles
#define OFF_NW2 98304    // 32 tiles
#define OFF_NW3 114688   // 32 tiles
#define OFF_TH  131072   // 32 tiles
#define OFF_A3  147456   // 4 tiles
#define TOT_TILES 292

// Pack all weights (f32) into MFMA A-fragment order, bf16, one launch.
// tile = kt*8+nt; lane holds n = nt*16+(lane&15), k = kt*32+(lane>>4)*8+i.
__global__ __launch_bounds__(256) void repack_all(
    const float* __restrict__ aw1, const float* __restrict__ aw2,
    const float* __restrict__ nw1, const float* __restrict__ nw2,
    const float* __restrict__ nw3, const float* __restrict__ thw,
    const float* __restrict__ aw3, __bf16* __restrict__ dst) {
    int t = blockIdx.x * 256 + threadIdx.x;
    if (t >= TOT_TILES * 512) return;
    int tile = t >> 9;
    int i    = t & 7;
    int lane = (t >> 3) & 63;
    int krow = ((lane >> 4) << 3) + i;
    int ncol = lane & 15;
    float v;
    if (tile >= 288) {                   // A3: aw3 [128][4] padded to 16 cols
        int k = (tile - 288) * 32 + krow;
        v = (ncol < 4) ? aw3[k * 4 + ncol] : 0.f;
    } else {
        const float* src; int lt;
        if      (tile < 96)  { src = aw1; lt = tile; }        // K=384
        else if (tile < 128) { src = aw2; lt = tile - 96; }
        else if (tile < 192) { src = nw1; lt = tile - 128; }  // K=256
        else if (tile < 224) { src = nw2; lt = tile - 192; }
        else if (tile < 256) { src = nw3; lt = tile - 224; }
        else                 { src = thw; lt = tile - 256; }
        int nt = lt & 7;
        int kt = lt >> 3;
        v = src[(kt * 32 + krow) * DIM + nt * 16 + ncol];
    }
    dst[t] = (__bf16)v;
}

// fast gelu: 0.5x(1+tanh(u)) = x - x/(exp(2u)+1)  (~8 VALU incl native rcp)
__device__ __forceinline__ float gelu_f(float x) {
    float y = x * fmaf(0.0713548163f, x * x, 1.5957691216f);  // 2u
    float r = __builtin_amdgcn_rcpf(__expf(y) + 1.f);
    return x - x * r;
}

__device__ __forceinline__ bf16x4 cvt4(float4 v) {
    bf16x4 r;
    r[0] = (__bf16)v.x; r[1] = (__bf16)v.y; r[2] = (__bf16)v.z; r[3] = (__bf16)v.w;
    return r;
}

// actmode: 0 = relu, 1 = gelu.
__device__ __forceinline__ void store_act(f32x4 acc[2], const float* __restrict__ bias,
                                          __bf16* y, int sy, int actmode,
                                          int wv, int lane) {
    const int mrow = lane & 15;
    const int kgrp = (lane >> 4) & 3;
    const int nb = wv * 16 + kgrp * 4;
    float b0 = bias[nb], b1 = bias[nb + 1], b2 = bias[nb + 2], b3 = bias[nb + 3];
#pragma unroll
    for (int mf = 0; mf < 2; ++mf) {
        bf16x4 pk;
        float vv[4] = {acc[mf][0] + b0, acc[mf][1] + b1, acc[mf][2] + b2, acc[mf][3] + b3};
#pragma unroll
        for (int r = 0; r < 4; ++r) {
            float v = vv[r];
            v = actmode == 0 ? fmaxf(v, 0.f) : gelu_f(v);
            pk[r] = (__bf16)v;
        }
        *reinterpret_cast<bf16x4*>(y + (mf * 16 + mrow) * sy + nb) = pk;
    }
}

#define ZERO2(A) do { A[0] = (f32x4){0.f,0.f,0.f,0.f}; A[1] = (f32x4){0.f,0.f,0.f,0.f}; } while (0)

// ---- generic 128->128 row GEMM (64 rows/block, 8 waves): out = in @ Wfrag (+bias) ----
__global__ __launch_bounds__(512) void mm128(const float* __restrict__ in,
                                             float* __restrict__ outp,
                                             const __bf16* __restrict__ wfrag,
                                             const float* __restrict__ bias) {
    __shared__ __bf16 sP[64 * 136];
    const int tid  = threadIdx.x;
    const int wv   = tid >> 6;
    const int lane = tid & 63;
    const int mrow = lane & 15;
    const int kgrp = lane >> 4;
    const int base = blockIdx.x * 64;

#pragma unroll
    for (int c = 0; c < 4; ++c) {
        int idx = c * 512 + tid;
        int m  = idx >> 5;
        int jv = idx & 31;
        int row = base + m;
        float4 v = make_float4(0.f, 0.f, 0.f, 0.f);
        if (row < N_NODES) v = *reinterpret_cast<const float4*>(in + (long)row * DIM + jv * 4);
        *reinterpret_cast<bf16x4*>(&sP[m * 136 + jv * 4]) = cvt4(v);
    }
    __syncthreads();

    f32x4 acc[4];
#pragma unroll
    for (int mf = 0; mf < 4; ++mf) acc[mf] = (f32x4){0.f, 0.f, 0.f, 0.f};
#pragma unroll
    for (int kt = 0; kt < 4; ++kt) {
        bf16x8 a = *reinterpret_cast<const bf16x8*>(wfrag + ((kt * 8 + wv) * 64 + lane) * 8);
        const int kb = kt * 32 + kgrp * 8;
#pragma unroll
        for (int mf = 0; mf < 4; ++mf) {
            bf16x8 b = *reinterpret_cast<const bf16x8*>(sP + (mf * 16 + mrow) * 136 + kb);
            acc[mf] = __builtin_amdgcn_mfma_f32_16x16x32_bf16(a, b, acc[mf], 0, 0, 0);
        }
    }
    const int nb = wv * 16 + kgrp * 4;
    float b0 = 0.f, b1 = 0.f, b2 = 0.f, b3 = 0.f;
    if (bias) { b0 = bias[nb]; b1 = bias[nb + 1]; b2 = bias[nb + 2]; b3 = bias[nb + 3]; }
#pragma unroll
    for (int mf = 0; mf < 4; ++mf) {
        int row = base + mf * 16 + mrow;
        if (row < N_NODES) {
            float4 o = make_float4(acc[mf][0] + b0, acc[mf][1] + b1,
                                   acc[mf][2] + b2, acc[mf][3] + b3);
            *reinterpret_cast<float4*>(outp + (long)row * DIM + nb) = o;
        }
    }
}

// ---- fused kernel: one block = 1 node (30 edges padded to 32), 512 thr = 8 waves ----
// r13 structure (proven 149.4 us) with the hi contribution folded into P1 as a
// BROADCAST-B K-extension: all edges share hi = h[node], so the hi-part B
// fragment is row-invariant -> one conflict-free broadcast bf16x8 read per kg
// from sHI. Deletes the separate yhi mm128 kernel + its 10 MB round-trip.
// 4 barriers. Occupancy law (r1..r15): waves/SIMD ~ floor(256/VGPR); keep VGPR
// minimal. r14/r15 lessons: don't trade occupancy for LDS reads; don't fold
// work that breaks the coalesced/MFMA structure.
__global__ __launch_bounds__(512, 4) void gnn_fused(
    const float* __restrict__ h, const float* __restrict__ e, const int* __restrict__ eidx,
    const float* __restrict__ ab1, const float* __restrict__ ab2, const float* __restrict__ ab3,
    const float* __restrict__ nb1, const float* __restrict__ nb2, const float* __restrict__ nb3,
    const __bf16* __restrict__ wp, float* __restrict__ pre_out) {

    __shared__ __bf16 S[8704];        // staging e|hj (stride 264, 8448 used);
                                      // after P1: S' = node2-out @0, A2 = att2-out @4352 (stride 136)
    __shared__ __bf16 Y1[32 * 136];   // att1-out
    __shared__ __bf16 Y2[32 * 136];   // node1-out
    __shared__ __bf16 sHI[128];       // h[node] row (broadcast B for hi k-tiles)
    __shared__ float  sW[32][4];      // softmax weights (rows 30/31 = 0)

    const int tid  = threadIdx.x;
    const int wv   = tid >> 6;
    const int lane = tid & 63;
    const int mrow = lane & 15;
    const int kg   = (lane >> 4) & 3;
    const int node = blockIdx.x;
    const long ebase = (long)node * KNEI;

    // ---- P0: stage e|hj (f32 -> bf16), pad rows 30/31 = 0; stage h[node] ----
    if (tid < 32) {
        float4 hv = *reinterpret_cast<const float4*>(h + (long)node * DIM + tid * 4);
        *reinterpret_cast<bf16x4*>(&sHI[tid * 4]) = cvt4(hv);
    }
#pragma unroll
    for (int c = 0; c < 2; ++c) {
        int idx = c * 512 + tid;
        int m  = idx >> 5;   // row 0..31
        int jv = idx & 31;   // float4 col
        float4 ev = make_float4(0.f, 0.f, 0.f, 0.f), hjv = ev;
        if (m < KNEI) {
            long ge = ebase + m;
            ev  = *reinterpret_cast<const float4*>(e + ge * DIM + jv * 4);
            int dstn = eidx[EDGES + ge];
            hjv = *reinterpret_cast<const float4*>(h + (long)dstn * DIM + jv * 4);
        }
        *reinterpret_cast<bf16x4*>(&S[m * 264 + jv * 4])       = cvt4(ev);
        *reinterpret_cast<bf16x4*>(&S[m * 264 + 128 + jv * 4]) = cvt4(hjv);
    }
    __syncthreads();   // b0

    // ---- P1: MERGED layer-1: att (K=384: hi broadcast + e|hj) & node (K=256) ----
    {
        f32x4 aa[2], an[2];
        ZERO2(aa); ZERO2(an);
        const __bf16* wA = wp + OFF_AW1 + 16384;   // att_w1 e|hj part (kt 4..11)
        const __bf16* wN = wp + OFF_NW1;
#pragma unroll
        for (int kt = 0; kt < 8; ++kt) {
            const int kb = kt * 32 + kg * 8;
            bf16x8 b0 = *reinterpret_cast<const bf16x8*>(S + mrow * 264 + kb);
            bf16x8 b1 = *reinterpret_cast<const bf16x8*>(S + (16 + mrow) * 264 + kb);
            bf16x8 a0 = *reinterpret_cast<const bf16x8*>(wA + ((kt * 8 + wv) * 64 + lane) * 8);
            aa[0] = __builtin_amdgcn_mfma_f32_16x16x32_bf16(a0, b0, aa[0], 0, 0, 0);
            aa[1] = __builtin_amdgcn_mfma_f32_16x16x32_bf16(a0, b1, aa[1], 0, 0, 0);
            bf16x8 a1 = *reinterpret_cast<const bf16x8*>(wN + ((kt * 8 + wv) * 64 + lane) * 8);
            an[0] = __builtin_amdgcn_mfma_f32_16x16x32_bf16(a1, b0, an[0], 0, 0, 0);
            an[1] = __builtin_amdgcn_mfma_f32_16x16x32_bf16(a1, b1, an[1], 0, 0, 0);
        }
        // hi part (att only): B rows all equal h[node] -> broadcast read
#pragma unroll
        for (int kt = 0; kt < 4; ++kt) {
            const int kb = kt * 32 + kg * 8;
            bf16x8 bh = *reinterpret_cast<const bf16x8*>(sHI + kb);
            bf16x8 a0 = *reinterpret_cast<const bf16x8*>(wp + OFF_AW1 + ((kt * 8 + wv) * 64 + lane) * 8);
            aa[0] = __builtin_amdgcn_mfma_f32_16x16x32_bf16(a0, bh, aa[0], 0, 0, 0);
            aa[1] = __builtin_amdgcn_mfma_f32_16x16x32_bf16(a0, bh, aa[1], 0, 0, 0);
        }
        store_act(aa, ab1, Y1, 136, 0, wv, lane);
        store_act(an, nb1, Y2, 136, 1, wv, lane);
    }
    __syncthreads();   // b1 (S reads done; S free for S'/A2)

    // ---- P2: wave-split layer-2 (K=128): att2 -> A2 (relu), node2 -> S' (gelu) ----
    {
        const bool isatt = (wv < 4);
        const int w4 = isatt ? wv : (wv - 4);
        const __bf16* B = isatt ? Y1 : Y2;
        const __bf16* W = wp + (isatt ? OFF_AW2 : OFF_NW2);
        const float* bias = isatt ? ab2 : nb2;
        __bf16* dst = S + (isatt ? 4352 : 0);
        f32x4 acc[2][2];
        ZERO2(acc[0]); ZERO2(acc[1]);
#pragma unroll
        for (int kt = 0; kt < 4; ++kt) {
            const int kb = kt * 32 + kg * 8;
            bf16x8 b0 = *reinterpret_cast<const bf16x8*>(B + mrow * 136 + kb);
            bf16x8 b1 = *reinterpret_cast<const bf16x8*>(B + (16 + mrow) * 136 + kb);
#pragma unroll
            for (int j = 0; j < 2; ++j) {
                bf16x8 a = *reinterpret_cast<const bf16x8*>(W + (size_t)((kt * 8 + w4 * 2 + j) * 64 + lane) * 8);
                acc[j][0] = __builtin_amdgcn_mfma_f32_16x16x32_bf16(a, b0, acc[j][0], 0, 0, 0);
                acc[j][1] = __builtin_amdgcn_mfma_f32_16x16x32_bf16(a, b1, acc[j][1], 0, 0, 0);
            }
        }
#pragma unroll
        for (int j = 0; j < 2; ++j) {
            const int f = w4 * 32 + j * 16 + kg * 4;
            float b0 = bias[f], b1 = bias[f + 1], b2 = bias[f + 2], b3 = bias[f + 3];
#pragma unroll
            for (int mf = 0; mf < 2; ++mf) {
                float vv[4] = {acc[j][mf][0] + b0, acc[j][mf][1] + b1,
                               acc[j][mf][2] + b2, acc[j][mf][3] + b3};
                bf16x4 pk;
#pragma unroll
                for (int r = 0; r < 4; ++r) {
                    float v = vv[r];
                    pk[r] = (__bf16)(isatt ? fmaxf(v, 0.f) : gelu_f(v));
                }
                *reinterpret_cast<bf16x4*>(dst + (mf * 16 + mrow) * 136 + f) = pk;
            }
        }
    }
    __syncthreads();   // b2 (Y1/Y2 reads done; S' and A2 ready)

    // ---- P3: wave 0: logits via MFMA + softmax; all waves: node3 (V in regs) ----
    if (wv == 0) {
        const __bf16* A2 = S + 4352;
        f32x4 la[2];
        ZERO2(la);
#pragma unroll
        for (int kt = 0; kt < 4; ++kt) {
            const int kb = kt * 32 + kg * 8;
            bf16x8 b0 = *reinterpret_cast<const bf16x8*>(A2 + mrow * 136 + kb);
            bf16x8 b1 = *reinterpret_cast<const bf16x8*>(A2 + (16 + mrow) * 136 + kb);
            bf16x8 a = *reinterpret_cast<const bf16x8*>(wp + OFF_A3 + ((kt * 64) + lane) * 8);
            la[0] = __builtin_amdgcn_mfma_f32_16x16x32_bf16(a, b0, la[0], 0, 0, 0);
            la[1] = __builtin_amdgcn_mfma_f32_16x16x32_bf16(a, b1, la[1], 0, 0, 0);
        }
        if (lane < 16) {   // lane = edge m; heads 0-3 in regs (kg==0 slice)
            const float sc = 0.17677669529f;   // 1/sqrt(32)
            float v0[4], v1[4], mx[4];
            const bool pad1 = (16 + lane) >= KNEI;
#pragma unroll
            for (int r = 0; r < 4; ++r) {
                v0[r] = (la[0][r] + ab3[r]) * sc;
                v1[r] = pad1 ? -1e30f : (la[1][r] + ab3[r]) * sc;
                mx[r] = fmaxf(v0[r], v1[r]);
            }
#pragma unroll
            for (int msk = 1; msk <= 8; msk <<= 1)
#pragma unroll
                for (int r = 0; r < 4; ++r) mx[r] = fmaxf(mx[r], __shfl_xor(mx[r], msk));
            float e0[4], e1[4], sm[4];
#pragma unroll
            for (int r = 0; r < 4; ++r) {
                e0[r] = __expf(v0[r] - mx[r]);
                e1[r] = __expf(v1[r] - mx[r]);   // pad -> 0
                sm[r] = e0[r] + e1[r];
            }
#pragma unroll
            for (int msk = 1; msk <= 8; msk <<= 1)
#pragma unroll
                for (int r = 0; r < 4; ++r) sm[r] += __shfl_xor(sm[r], msk);
            float i0 = __builtin_amdgcn_rcpf(sm[0]), i1 = __builtin_amdgcn_rcpf(sm[1]);
            float i2 = __builtin_amdgcn_rcpf(sm[2]), i3 = __builtin_amdgcn_rcpf(sm[3]);
            float4 w0 = make_float4(e0[0] * i0, e0[1] * i1, e0[2] * i2, e0[3] * i3);
            float4 w1 = make_float4(e1[0] * i0, e1[1] * i1, e1[2] * i2, e1[3] * i3);
            *reinterpret_cast<float4*>(&sW[lane][0])      = w0;
            *reinterpret_cast<float4*>(&sW[16 + lane][0]) = w1;   // rows 30/31 -> 0
        }
    }
    f32x4 v2[2];
    ZERO2(v2);
#pragma unroll
    for (int kt = 0; kt < 4; ++kt) {
        const int kb = kt * 32 + kg * 8;
        bf16x8 b0 = *reinterpret_cast<const bf16x8*>(S + mrow * 136 + kb);
        bf16x8 b1 = *reinterpret_cast<const bf16x8*>(S + (16 + mrow) * 136 + kb);
        bf16x8 a = *reinterpret_cast<const bf16x8*>(wp + OFF_NW3 + (size_t)((kt * 8 + wv) * 64 + lane) * 8);
        v2[0] = __builtin_amdgcn_mfma_f32_16x16x32_bf16(a, b0, v2[0], 0, 0, 0);
        v2[1] = __builtin_amdgcn_mfma_f32_16x16x32_bf16(a, b1, v2[1], 0, 0, 0);
    }
    __syncthreads();   // b3 (sW visible; V in regs)

    // ---- P4: fused aggregation epilogue: pre[node][n] = sum_m w[m]*(V+nb3) ----
    {
        const int hh = wv >> 1;           // head of this wave's 16-feature slice
        float wgt0 = sW[mrow][hh];        // edge m = mrow      (mf=0)
        float wgt1 = sW[16 + mrow][hh];   // edge m = 16 + mrow (mf=1)
        float part[4];
#pragma unroll
        for (int r = 0; r < 4; ++r)
            part[r] = wgt0 * v2[0][r] + wgt1 * v2[1][r];
#pragma unroll
        for (int msk = 1; msk <= 8; msk <<= 1)
#pragma unroll
            for (int r = 0; r < 4; ++r)
                part[r] += __shfl_xor(part[r], msk);
        if (mrow == 0) {                  // lanes 0,16,32,48 -> kg 0..3
            const int nb = wv * 16 + kg * 4;
            float4 o = make_float4(part[0] + nb3[nb],     part[1] + nb3[nb + 1],
                                   part[2] + nb3[nb + 2], part[3] + nb3[nb + 3]);
            *reinterpret_cast<float4*>(pre_out + (long)node * DIM + nb) = o;
        }
    }
}

extern "C" void kernel_launch(void* const* d_in, const int* in_sizes, int n_in,
                              void* d_out, int out_size, void* d_ws, size_t ws_size,
                              hipStream_t stream) {
    const float* h   = (const float*)d_in[0];
    const float* e   = (const float*)d_in[1];
    const int*   ei  = (const int*)d_in[2];
    const float* aw1 = (const float*)d_in[3];
    const float* ab1 = (const float*)d_in[4];
    const float* aw2 = (const float*)d_in[5];
    const float* ab2 = (const float*)d_in[6];
    const float* aw3 = (const float*)d_in[7];
    const float* ab3 = (const float*)d_in[8];
    const float* nw1 = (const float*)d_in[9];
    const float* nb1 = (const float*)d_in[10];
    const float* nw2 = (const float*)d_in[11];
    const float* nb2 = (const float*)d_in[12];
    const float* nw3 = (const float*)d_in[13];
    const float* nb3 = (const float*)d_in[14];
    const float* thw = (const float*)d_in[15];
    float* out = (float*)d_out;
    __bf16* wp = (__bf16*)d_ws;

    // all-weight repack (f32 -> bf16 MFMA-fragment order), one launch
    repack_all<<<(TOT_TILES * 512 + 255) / 256, 256, 0, stream>>>(
        aw1, aw2, nw1, nw2, nw3, thw, aw3, wp);

    gnn_fused<<<N_NODES, 512, 0, stream>>>(h, e, ei, ab1, ab2, ab3,
                                           nb1, nb2, nb3, wp, out);
    // out = pre @ to_h_w (in-place)
    mm128<<<(N_NODES + 63) / 64, 512, 0, stream>>>(out, out, wp + OFF_TH, nullptr);
}

// Round 17
// 149.386 us; speedup vs baseline: 1.4147x; 1.2602x over previous
//
#include <hip/hip_runtime.h>
#include <hip/hip_bf16.h>

#define N_NODES 10000
#define KNEI    30
#define DIM     128
#define EDGES   (N_NODES * KNEI)

typedef __attribute__((ext_vector_type(4))) float  f32x4;
typedef __attribute__((ext_vector_type(8))) __bf16 bf16x8;
typedef __attribute__((ext_vector_type(4))) __bf16 bf16x4;

// packed bf16 weight offsets in d_ws (element units); per-matrix fragment tiles
// AW1 (K=384, kt0..3 = hi part, kt4..11 = e|hj), others K=128/256, Ntiles=8.
// A3 = att_w3 [128][4] zero-padded to N=16 (1 n-tile, 4 k-tiles).
#define OFF_AW1 0        // 96 tiles
#define OFF_AW2 49152    // 32 tiles
#define OFF_NW1 65536    // 64 tiles
#define OFF_NW2 98304    // 32 tiles
#define OFF_NW3 114688   // 32 tiles
#define OFF_TH  131072   // 32 tiles
#define OFF_A3  147456   // 4 tiles
#define TOT_TILES 292
#define YHI_BYTE_OFF (300 * 1024)   // f32 yhi[N][128] after weights

// Pack all weights (f32) into MFMA A-fragment order, bf16, one launch.
// tile = kt*8+nt; lane holds n = nt*16+(lane&15), k = kt*32+(lane>>4)*8+i.
__global__ __launch_bounds__(256) void repack_all(
    const float* __restrict__ aw1, const float* __restrict__ aw2,
    const float* __restrict__ nw1, const float* __restrict__ nw2,
    const float* __restrict__ nw3, const float* __restrict__ thw,
    const float* __restrict__ aw3, __bf16* __restrict__ dst) {
    int t = blockIdx.x * 256 + threadIdx.x;
    if (t >= TOT_TILES * 512) return;
    int tile = t >> 9;
    int i    = t & 7;
    int lane = (t >> 3) & 63;
    int krow = ((lane >> 4) << 3) + i;
    int ncol = lane & 15;
    float v;
    if (tile >= 288) {                   // A3: aw3 [128][4] padded to 16 cols
        int k = (tile - 288) * 32 + krow;
        v = (ncol < 4) ? aw3[k * 4 + ncol] : 0.f;
    } else {
        const float* src; int lt;
        if      (tile < 96)  { src = aw1; lt = tile; }        // K=384
        else if (tile < 128) { src = aw2; lt = tile - 96; }
        else if (tile < 192) { src = nw1; lt = tile - 128; }  // K=256
        else if (tile < 224) { src = nw2; lt = tile - 192; }
        else if (tile < 256) { src = nw3; lt = tile - 224; }
        else                 { src = thw; lt = tile - 256; }
        int nt = lt & 7;
        int kt = lt >> 3;
        v = src[(kt * 32 + krow) * DIM + nt * 16 + ncol];
    }
    dst[t] = (__bf16)v;
}

// fast gelu: 0.5x(1+tanh(u)) = x - x/(exp(2u)+1)  (~8 VALU incl native rcp)
__device__ __forceinline__ float gelu_f(float x) {
    float y = x * fmaf(0.0713548163f, x * x, 1.5957691216f);  // 2u
    float r = __builtin_amdgcn_rcpf(__expf(y) + 1.f);
    return x - x * r;
}

__device__ __forceinline__ bf16x4 cvt4(float4 v) {
    bf16x4 r;
    r[0] = (__bf16)v.x; r[1] = (__bf16)v.y; r[2] = (__bf16)v.z; r[3] = (__bf16)v.w;
    return r;
}

// actmode: 0 = relu, 1 = gelu. bias may be a per-node yhi row.
__device__ __forceinline__ void store_act(f32x4 acc[2], const float* __restrict__ bias,
                                          __bf16* y, int sy, int actmode,
                                          int wv, int lane) {
    const int mrow = lane & 15;
    const int kgrp = (lane >> 4) & 3;
    const int nb = wv * 16 + kgrp * 4;
    float b0 = bias[nb], b1 = bias[nb + 1], b2 = bias[nb + 2], b3 = bias[nb + 3];
#pragma unroll
    for (int mf = 0; mf < 2; ++mf) {
        bf16x4 pk;
        float vv[4] = {acc[mf][0] + b0, acc[mf][1] + b1, acc[mf][2] + b2, acc[mf][3] + b3};
#pragma unroll
        for (int r = 0; r < 4; ++r) {
            float v = vv[r];
            v = actmode == 0 ? fmaxf(v, 0.f) : gelu_f(v);
            pk[r] = (__bf16)v;
        }
        *reinterpret_cast<bf16x4*>(y + (mf * 16 + mrow) * sy + nb) = pk;
    }
}

#define ZERO2(A) do { A[0] = (f32x4){0.f,0.f,0.f,0.f}; A[1] = (f32x4){0.f,0.f,0.f,0.f}; } while (0)

// ---- generic 128->128 row GEMM (64 rows/block, 8 waves): out = in @ Wfrag (+bias) ----
__global__ __launch_bounds__(512) void mm128(const float* __restrict__ in,
                                             float* __restrict__ outp,
                                             const __bf16* __restrict__ wfrag,
                                             const float* __restrict__ bias) {
    __shared__ __bf16 sP[64 * 136];
    const int tid  = threadIdx.x;
    const int wv   = tid >> 6;
    const int lane = tid & 63;
    const int mrow = lane & 15;
    const int kgrp = lane >> 4;
    const int base = blockIdx.x * 64;

#pragma unroll
    for (int c = 0; c < 4; ++c) {
        int idx = c * 512 + tid;
        int m  = idx >> 5;
        int jv = idx & 31;
        int row = base + m;
        float4 v = make_float4(0.f, 0.f, 0.f, 0.f);
        if (row < N_NODES) v = *reinterpret_cast<const float4*>(in + (long)row * DIM + jv * 4);
        *reinterpret_cast<bf16x4*>(&sP[m * 136 + jv * 4]) = cvt4(v);
    }
    __syncthreads();

    f32x4 acc[4];
#pragma unroll
    for (int mf = 0; mf < 4; ++mf) acc[mf] = (f32x4){0.f, 0.f, 0.f, 0.f};
#pragma unroll
    for (int kt = 0; kt < 4; ++kt) {
        bf16x8 a = *reinterpret_cast<const bf16x8*>(wfrag + ((kt * 8 + wv) * 64 + lane) * 8);
        const int kb = kt * 32 + kgrp * 8;
#pragma unroll
        for (int mf = 0; mf < 4; ++mf) {
            bf16x8 b = *reinterpret_cast<const bf16x8*>(sP + (mf * 16 + mrow) * 136 + kb);
            acc[mf] = __builtin_amdgcn_mfma_f32_16x16x32_bf16(a, b, acc[mf], 0, 0, 0);
        }
    }
    const int nb = wv * 16 + kgrp * 4;
    float b0 = 0.f, b1 = 0.f, b2 = 0.f, b3 = 0.f;
    if (bias) { b0 = bias[nb]; b1 = bias[nb + 1]; b2 = bias[nb + 2]; b3 = bias[nb + 3]; }
#pragma unroll
    for (int mf = 0; mf < 4; ++mf) {
        int row = base + mf * 16 + mrow;
        if (row < N_NODES) {
            float4 o = make_float4(acc[mf][0] + b0, acc[mf][1] + b1,
                                   acc[mf][2] + b2, acc[mf][3] + b3);
            *reinterpret_cast<float4*>(outp + (long)row * DIM + nb) = o;
        }
    }
}

// ---- fused kernel: one block = 1 node (30 edges padded to 32), 512 thr = 8 waves ----
// 4 barriers. P1 = MERGED layer-1 (att1 + node1 share each ds_read of S).
// P2 = wave-split layer-2: waves 0-3 att2 -> relu -> A2; waves 4-7 node2 -> gelu -> S'.
// P3 = node3 (V in regs, all waves); wave 0 also: logits = A2 @ A3frag via 4 MFMA
//      (matrix pipe) + lane<16 softmax -> sW.
// P4 = fused aggregation epilogue.
// PROVEN OPTIMUM (r13 = 149.4 us). r14 (wider n-slices, occ 84->44), r15
// (folded matvecs, uncoalesced), r16 (hi broadcast, VGPR 32->48) ALL regressed.
// Occupancy law (r1..r16): waves/SIMD ~ floor(256/VGPR), 512-thr blocks;
// VGPR 32 -> 85% occ; 36 -> 64%; 48+ -> 44%. Do not perturb register pressure.
__global__ __launch_bounds__(512, 4) void gnn_fused(
    const float* __restrict__ h, const float* __restrict__ e, const int* __restrict__ eidx,
    const float* __restrict__ yhi,
    const float* __restrict__ ab2, const float* __restrict__ ab3,
    const float* __restrict__ nb1, const float* __restrict__ nb2, const float* __restrict__ nb3,
    const __bf16* __restrict__ wp, float* __restrict__ pre_out) {

    __shared__ __bf16 S[8704];        // staging e|hj (stride 264, 8448 used);
                                      // after P1: S' = node2-out @0, A2 = att2-out @4352 (stride 136)
    __shared__ __bf16 Y1[32 * 136];   // att1-out
    __shared__ __bf16 Y2[32 * 136];   // node1-out
    __shared__ float  sW[32][4];      // softmax weights (rows 30/31 = 0)

    const int tid  = threadIdx.x;
    const int wv   = tid >> 6;
    const int lane = tid & 63;
    const int mrow = lane & 15;
    const int kg   = (lane >> 4) & 3;
    const int node = blockIdx.x;
    const long ebase = (long)node * KNEI;

    // ---- P0: stage e|hj (f32 -> bf16), pad rows 30/31 = 0 ----
#pragma unroll
    for (int c = 0; c < 2; ++c) {
        int idx = c * 512 + tid;
        int m  = idx >> 5;   // row 0..31
        int jv = idx & 31;   // float4 col
        float4 ev = make_float4(0.f, 0.f, 0.f, 0.f), hjv = ev;
        if (m < KNEI) {
            long ge = ebase + m;
            ev  = *reinterpret_cast<const float4*>(e + ge * DIM + jv * 4);
            int dstn = eidx[EDGES + ge];
            hjv = *reinterpret_cast<const float4*>(h + (long)dstn * DIM + jv * 4);
        }
        *reinterpret_cast<bf16x4*>(&S[m * 264 + jv * 4])       = cvt4(ev);
        *reinterpret_cast<bf16x4*>(&S[m * 264 + 128 + jv * 4]) = cvt4(hjv);
    }
    __syncthreads();   // b0

    // ---- P1: MERGED layer-1 (K=256): att1 & node1 share S b-reads ----
    {
        f32x4 aa[2], an[2];
        ZERO2(aa); ZERO2(an);
        const __bf16* wA = wp + OFF_AW1 + 16384;   // att_w1 e|hj part (kt 4..11)
        const __bf16* wN = wp + OFF_NW1;
#pragma unroll
        for (int kt = 0; kt < 8; ++kt) {
            const int kb = kt * 32 + kg * 8;
            bf16x8 b0 = *reinterpret_cast<const bf16x8*>(S + mrow * 264 + kb);
            bf16x8 b1 = *reinterpret_cast<const bf16x8*>(S + (16 + mrow) * 264 + kb);
            bf16x8 a0 = *reinterpret_cast<const bf16x8*>(wA + ((kt * 8 + wv) * 64 + lane) * 8);
            aa[0] = __builtin_amdgcn_mfma_f32_16x16x32_bf16(a0, b0, aa[0], 0, 0, 0);
            aa[1] = __builtin_amdgcn_mfma_f32_16x16x32_bf16(a0, b1, aa[1], 0, 0, 0);
            bf16x8 a1 = *reinterpret_cast<const bf16x8*>(wN + ((kt * 8 + wv) * 64 + lane) * 8);
            an[0] = __builtin_amdgcn_mfma_f32_16x16x32_bf16(a1, b0, an[0], 0, 0, 0);
            an[1] = __builtin_amdgcn_mfma_f32_16x16x32_bf16(a1, b1, an[1], 0, 0, 0);
        }
        store_act(aa, yhi + (long)node * DIM, Y1, 136, 0, wv, lane);
        store_act(an, nb1, Y2, 136, 1, wv, lane);
    }
    __syncthreads();   // b1 (S reads done; S free for S'/A2)

    // ---- P2: wave-split layer-2 (K=128): att2 -> A2 (relu), node2 -> S' (gelu) ----
    {
        const bool isatt = (wv < 4);
        const int w4 = isatt ? wv : (wv - 4);
        const __bf16* B = isatt ? Y1 : Y2;
        const __bf16* W = wp + (isatt ? OFF_AW2 : OFF_NW2);
        const float* bias = isatt ? ab2 : nb2;
        __bf16* dst = S + (isatt ? 4352 : 0);
        f32x4 acc[2][2];
        ZERO2(acc[0]); ZERO2(acc[1]);
#pragma unroll
        for (int kt = 0; kt < 4; ++kt) {
            const int kb = kt * 32 + kg * 8;
            bf16x8 b0 = *reinterpret_cast<const bf16x8*>(B + mrow * 136 + kb);
            bf16x8 b1 = *reinterpret_cast<const bf16x8*>(B + (16 + mrow) * 136 + kb);
#pragma unroll
            for (int j = 0; j < 2; ++j) {
                bf16x8 a = *reinterpret_cast<const bf16x8*>(W + (size_t)((kt * 8 + w4 * 2 + j) * 64 + lane) * 8);
                acc[j][0] = __builtin_amdgcn_mfma_f32_16x16x32_bf16(a, b0, acc[j][0], 0, 0, 0);
                acc[j][1] = __builtin_amdgcn_mfma_f32_16x16x32_bf16(a, b1, acc[j][1], 0, 0, 0);
            }
        }
#pragma unroll
        for (int j = 0; j < 2; ++j) {
            const int f = w4 * 32 + j * 16 + kg * 4;
            float b0 = bias[f], b1 = bias[f + 1], b2 = bias[f + 2], b3 = bias[f + 3];
#pragma unroll
            for (int mf = 0; mf < 2; ++mf) {
                float vv[4] = {acc[j][mf][0] + b0, acc[j][mf][1] + b1,
                               acc[j][mf][2] + b2, acc[j][mf][3] + b3};
                bf16x4 pk;
#pragma unroll
                for (int r = 0; r < 4; ++r) {
                    float v = vv[r];
                    pk[r] = (__bf16)(isatt ? fmaxf(v, 0.f) : gelu_f(v));
                }
                *reinterpret_cast<bf16x4*>(dst + (mf * 16 + mrow) * 136 + f) = pk;
            }
        }
    }
    __syncthreads();   // b2 (Y1/Y2 reads done; S' and A2 ready)

    // ---- P3: wave 0: logits via MFMA + softmax; all waves: node3 (V in regs) ----
    if (wv == 0) {
        const __bf16* A2 = S + 4352;
        f32x4 la[2];
        ZERO2(la);
#pragma unroll
        for (int kt = 0; kt < 4; ++kt) {
            const int kb = kt * 32 + kg * 8;
            bf16x8 b0 = *reinterpret_cast<const bf16x8*>(A2 + mrow * 136 + kb);
            bf16x8 b1 = *reinterpret_cast<const bf16x8*>(A2 + (16 + mrow) * 136 + kb);
            bf16x8 a = *reinterpret_cast<const bf16x8*>(wp + OFF_A3 + ((kt * 64) + lane) * 8);
            la[0] = __builtin_amdgcn_mfma_f32_16x16x32_bf16(a, b0, la[0], 0, 0, 0);
            la[1] = __builtin_amdgcn_mfma_f32_16x16x32_bf16(a, b1, la[1], 0, 0, 0);
        }
        if (lane < 16) {   // lane = edge m; heads 0-3 in regs (kg==0 slice)
            const float sc = 0.17677669529f;   // 1/sqrt(32)
            float v0[4], v1[4], mx[4];
            const bool pad1 = (16 + lane) >= KNEI;
#pragma unroll
            for (int r = 0; r < 4; ++r) {
                v0[r] = (la[0][r] + ab3[r]) * sc;
                v1[r] = pad1 ? -1e30f : (la[1][r] + ab3[r]) * sc;
                mx[r] = fmaxf(v0[r], v1[r]);
            }
#pragma unroll
            for (int msk = 1; msk <= 8; msk <<= 1)
#pragma unroll
                for (int r = 0; r < 4; ++r) mx[r] = fmaxf(mx[r], __shfl_xor(mx[r], msk));
            float e0[4], e1[4], sm[4];
#pragma unroll
            for (int r = 0; r < 4; ++r) {
                e0[r] = __expf(v0[r] - mx[r]);
                e1[r] = __expf(v1[r] - mx[r]);   // pad -> 0
                sm[r] = e0[r] + e1[r];
            }
#pragma unroll
            for (int msk = 1; msk <= 8; msk <<= 1)
#pragma unroll
                for (int r = 0; r < 4; ++r) sm[r] += __shfl_xor(sm[r], msk);
            float i0 = __builtin_amdgcn_rcpf(sm[0]), i1 = __builtin_amdgcn_rcpf(sm[1]);
            float i2 = __builtin_amdgcn_rcpf(sm[2]), i3 = __builtin_amdgcn_rcpf(sm[3]);
            float4 w0 = make_float4(e0[0] * i0, e0[1] * i1, e0[2] * i2, e0[3] * i3);
            float4 w1 = make_float4(e1[0] * i0, e1[1] * i1, e1[2] * i2, e1[3] * i3);
            *reinterpret_cast<float4*>(&sW[lane][0])      = w0;
            *reinterpret_cast<float4*>(&sW[16 + lane][0]) = w1;   // rows 30/31 -> 0
        }
    }
    f32x4 v2[2];
    ZERO2(v2);
#pragma unroll
    for (int kt = 0; kt < 4; ++kt) {
        const int kb = kt * 32 + kg * 8;
        bf16x8 b0 = *reinterpret_cast<const bf16x8*>(S + mrow * 136 + kb);
        bf16x8 b1 = *reinterpret_cast<const bf16x8*>(S + (16 + mrow) * 136 + kb);
        bf16x8 a = *reinterpret_cast<const bf16x8*>(wp + OFF_NW3 + (size_t)((kt * 8 + wv) * 64 + lane) * 8);
        v2[0] = __builtin_amdgcn_mfma_f32_16x16x32_bf16(a, b0, v2[0], 0, 0, 0);
        v2[1] = __builtin_amdgcn_mfma_f32_16x16x32_bf16(a, b1, v2[1], 0, 0, 0);
    }
    __syncthreads();   // b3 (sW visible; V in regs)

    // ---- P4: fused aggregation epilogue: pre[node][n] = sum_m w[m]*(V+nb3) ----
    {
        const int hh = wv >> 1;           // head of this wave's 16-feature slice
        float wgt0 = sW[mrow][hh];        // edge m = mrow      (mf=0)
        float wgt1 = sW[16 + mrow][hh];   // edge m = 16 + mrow (mf=1)
        float part[4];
#pragma unroll
        for (int r = 0; r < 4; ++r)
            part[r] = wgt0 * v2[0][r] + wgt1 * v2[1][r];
#pragma unroll
        for (int msk = 1; msk <= 8; msk <<= 1)
#pragma unroll
            for (int r = 0; r < 4; ++r)
                part[r] += __shfl_xor(part[r], msk);
        if (mrow == 0) {                  // lanes 0,16,32,48 -> kg 0..3
            const int nb = wv * 16 + kg * 4;
            float4 o = make_float4(part[0] + nb3[nb],     part[1] + nb3[nb + 1],
                                   part[2] + nb3[nb + 2], part[3] + nb3[nb + 3]);
            *reinterpret_cast<float4*>(pre_out + (long)node * DIM + nb) = o;
        }
    }
}

extern "C" void kernel_launch(void* const* d_in, const int* in_sizes, int n_in,
                              void* d_out, int out_size, void* d_ws, size_t ws_size,
                              hipStream_t stream) {
    const float* h   = (const float*)d_in[0];
    const float* e   = (const float*)d_in[1];
    const int*   ei  = (const int*)d_in[2];
    const float* aw1 = (const float*)d_in[3];
    const float* ab1 = (const float*)d_in[4];
    const float* aw2 = (const float*)d_in[5];
    const float* ab2 = (const float*)d_in[6];
    const float* aw3 = (const float*)d_in[7];
    const float* ab3 = (const float*)d_in[8];
    const float* nw1 = (const float*)d_in[9];
    const float* nb1 = (const float*)d_in[10];
    const float* nw2 = (const float*)d_in[11];
    const float* nb2 = (const float*)d_in[12];
    const float* nw3 = (const float*)d_in[13];
    const float* nb3 = (const float*)d_in[14];
    const float* thw = (const float*)d_in[15];
    float* out = (float*)d_out;
    __bf16* wp = (__bf16*)d_ws;
    float* yhi = (float*)((char*)d_ws + YHI_BYTE_OFF);

    // all-weight repack (f32 -> bf16 MFMA-fragment order), one launch
    repack_all<<<(TOT_TILES * 512 + 255) / 256, 256, 0, stream>>>(
        aw1, aw2, nw1, nw2, nw3, thw, aw3, wp);

    const int nblk = (N_NODES + 63) / 64;
    // yhi = h @ att_w1[0:128,:] + ab1   (hi part of att layer 1, per node)
    mm128<<<nblk, 512, 0, stream>>>(h, yhi, wp + OFF_AW1, ab1);

    gnn_fused<<<N_NODES, 512, 0, stream>>>(h, e, ei, yhi, ab2, ab3,
                                           nb1, nb2, nb3, wp, out);
    // out = pre @ to_h_w (in-place)
    mm128<<<nblk, 512, 0, stream>>>(out, out, wp + OFF_TH, nullptr);
}